// Round 13
// baseline (2774.237 us; speedup 1.0000x reference)
//
#include <hip/hip_runtime.h>

#define NPT 20000
#define DIMK 256
#define HD 128
#define KC 64
#define NT 17
#define NSLOT (KC*NT)          // 1088
#define SINK_IT 50
#define NBLK 250               // sinkhorn/cb blocks: 80 rows each
#define RPB 80
#define LGB 64                 // lloyd blocks
#define CPB 313                // lloyd points per block (64*313 >= 20000)

// ---- scratch offsets (floats) inside the T region of d_out ----
#define OFF_H     0
#define OFF_CL    (NPT*HD)                   // 2,560,000
#define OFF_Q     (OFF_CL + NPT*KC)
#define OFF_LS    (OFF_Q + KC*NPT)
#define OFF_LOGU  (OFF_LS + NPT*KC)
#define OFF_ORDER (OFF_LOGU + NPT)
#define OFF_TSV   (OFF_ORDER + NPT)
#define OFF_OFFS  (OFF_TSV + NPT)            // 32 ints
#define OFF_CENTS (OFF_OFFS + 32)            // 128 f
#define OFF_I0    (OFF_CENTS + 128)
#define OFF_SUB   (OFF_I0 + 32)
#define OFF_LLP   (OFF_SUB + 128)            // LGB*192
#define OFF_PMB   (OFF_LLP + LGB*192)        // NBLK*3*64 = 48000
#define OFF_PSB   (OFF_PMB + NBLK*3*64)
#define OFF_RUNT  (OFF_PSB + NBLK*3*64)      // 750 ints -> 768
#define OFF_PLM   (OFF_RUNT + 768)           // 256
#define OFF_PLS   (OFF_PLM + 256)            // 256
// end ~= 6.53M floats << 21.76M floats of T region

__device__ __forceinline__ void tf2x32(unsigned k0, unsigned k1,
                                       unsigned x0, unsigned x1,
                                       unsigned& o0, unsigned& o1) {
  unsigned ks0 = k0, ks1 = k1, ks2 = k0 ^ k1 ^ 0x1BD11BDAu;
  x0 += ks0; x1 += ks1;
  const int rot[2][4] = {{13,15,26,6},{17,29,16,24}};
  unsigned ks[3] = {ks0, ks1, ks2};
  #pragma unroll
  for (int i = 0; i < 5; ++i) {
    #pragma unroll
    for (int r = 0; r < 4; ++r) {
      int rr = rot[i & 1][r];
      x0 += x1;
      x1 = (x1 << rr) | (x1 >> (32 - rr));
      x1 ^= x0;
    }
    x0 += ks[(i+1)%3];
    x1 += ks[(i+2)%3] + (unsigned)(i+1);
  }
  o0 = x0; o1 = x1;
}

__device__ __forceinline__ void lse_merge(float& m, float& s, float m2, float s2) {
  float mn = fmaxf(m, m2);
  s = s*__expf(m - mn) + s2*__expf(m2 - mn);
  m = mn;
}

// ---------------- K1: key chain + randint i0 (verified R5) ----------------
__global__ void k_keys(unsigned* sub, int* i0p) {
  if (threadIdx.x != 0 || blockIdx.x != 0) return;
  unsigned key0 = 0u, key1 = 42u;
  unsigned c0, c1, s0, s1;
  tf2x32(key0, key1, 0u, 0u, c0, c1);
  tf2x32(key0, key1, 0u, 1u, s0, s1);
  key0 = c0; key1 = c1;
  unsigned k1a, k1b, k2a, k2b;
  tf2x32(s0, s1, 0u, 0u, k1a, k1b);
  tf2x32(s0, s1, 0u, 1u, k2a, k2b);
  unsigned h0, h1, l0, l1;
  tf2x32(k1a, k1b, 0u, 0u, h0, h1);
  tf2x32(k2a, k2b, 0u, 0u, l0, l1);
  unsigned hb = h0 ^ h1, lb = l0 ^ l1;
  unsigned span = 20000u;
  unsigned m1 = 65536u % span;
  unsigned mult = (unsigned)(((unsigned long long)m1 * m1) % span);  // 7296
  unsigned off32 = (hb % span) * mult + (lb % span);
  *i0p = (int)(off32 % span);
  sub[0] = 0u; sub[1] = 0u;
  for (int i = 1; i < KC; ++i) {
    tf2x32(key0, key1, 0u, 0u, c0, c1);
    tf2x32(key0, key1, 0u, 1u, s0, s1);
    key0 = c0; key1 = c1;
    sub[2*i] = s0; sub[2*i+1] = s1;
  }
}

// ---------------- K2: Q[step][i] = exp(gumbel) = -1/log(u) ----------------
__global__ __launch_bounds__(256) void k_gumbel(const unsigned* __restrict__ sub,
                                                float* __restrict__ Q) {
  int s = blockIdx.y + 1;
  int i = blockIdx.x * 256 + threadIdx.x;
  if (i >= NPT) return;
  unsigned o0, o1;
  tf2x32(sub[2*s], sub[2*s+1], 0u, (unsigned)i, o0, o1);
  unsigned bits = o0 ^ o1;
  unsigned fb = (bits >> 9) | 0x3f800000u;
  float u = __uint_as_float(fb) - 1.0f;
  if (u == 0.0f) u = 1.17549435e-38f;
  Q[(size_t)s*NPT + i] = -1.0f / logf(u);
}

// ---------------- K3: h = selu(emb @ W1 + b1) ----------------
__global__ __launch_bounds__(256) void k_gemm(const float* __restrict__ emb,
                                              const float* __restrict__ W1,
                                              const float* __restrict__ b1,
                                              float* __restrict__ h) {
  __shared__ float As[64][64];
  __shared__ float Bs[64][HD];
  const int m0 = blockIdx.x * 64;
  const int tid = threadIdx.x;
  const int tx = tid & 31;
  const int ty = tid >> 5;
  float acc[8][4];
  #pragma unroll
  for (int a = 0; a < 8; ++a)
    #pragma unroll
    for (int c = 0; c < 4; ++c) acc[a][c] = 0.f;

  for (int kc = 0; kc < DIMK; kc += 64) {
    #pragma unroll
    for (int it = 0; it < 4; ++it) {
      int f = it*256 + tid;
      int r = f >> 4;
      int kk = (f & 15) << 2;
      float4 v = make_float4(0.f,0.f,0.f,0.f);
      if (m0 + r < NPT)
        v = *(const float4*)(emb + (size_t)(m0 + r)*DIMK + kc + kk);
      As[kk+0][r] = v.x; As[kk+1][r] = v.y; As[kk+2][r] = v.z; As[kk+3][r] = v.w;
    }
    #pragma unroll
    for (int it = 0; it < 8; ++it) {
      int f = it*256 + tid;
      int kk = f >> 5;
      int cc = (f & 31) << 2;
      *(float4*)&Bs[kk][cc] = *(const float4*)(W1 + (size_t)(kc + kk)*HD + cc);
    }
    __syncthreads();
    #pragma unroll 8
    for (int kk = 0; kk < 64; ++kk) {
      float4 a0 = *(float4*)&As[kk][ty*8];
      float4 a1 = *(float4*)&As[kk][ty*8+4];
      float4 bb = *(float4*)&Bs[kk][tx*4];
      float av[8] = {a0.x,a0.y,a0.z,a0.w,a1.x,a1.y,a1.z,a1.w};
      float bv[4] = {bb.x,bb.y,bb.z,bb.w};
      #pragma unroll
      for (int a = 0; a < 8; ++a)
        #pragma unroll
        for (int c = 0; c < 4; ++c) acc[a][c] += av[a]*bv[c];
    }
    __syncthreads();
  }
  const float SC = 1.0507009873554805f, AL = 1.6732632423543772f;
  #pragma unroll
  for (int a = 0; a < 8; ++a) {
    int r = m0 + ty*8 + a;
    if (r >= NPT) continue;
    float4 o;
    float* po = &o.x;
    #pragma unroll
    for (int c = 0; c < 4; ++c) {
      float x = acc[a][c] + b1[tx*4 + c];
      float v = (x > 0.f) ? x : AL * expm1f(x);
      po[c] = SC * v;
    }
    *(float4*)(h + (size_t)r*HD + tx*4) = o;
  }
}

// ---------------- K4: c_learned = sqdist(h, protos[:64]) ----------------
__global__ __launch_bounds__(256) void k_cl(const float* __restrict__ h,
                                            const float* __restrict__ protos,
                                            float* __restrict__ cl) {
  __shared__ float ps[KC][129];
  __shared__ float hs[4][HD];
  const int tid = threadIdx.x;
  #pragma unroll
  for (int it = 0; it < 32; ++it) {
    int f = it*256 + tid;
    ps[f >> 7][f & 127] = protos[f];
  }
  const int i0r = blockIdx.x * 4;
  for (int f = tid; f < 4*HD; f += 256) {
    int rr = f >> 7, d = f & 127;
    int gi = i0r + rr;
    hs[rr][d] = (gi < NPT) ? h[(size_t)gi*HD + d] : 0.f;
  }
  __syncthreads();
  const int j = tid & 63, rq = tid >> 6;
  const int gi = i0r + rq;
  if (gi < NPT) {
    float dot = 0.f, hh = 0.f, pp = 0.f;
    #pragma unroll 8
    for (int d = 0; d < HD; ++d) {
      float a = hs[rq][d], b = ps[j][d];
      dot += a*b; hh += a*a; pp += b*b;
    }
    float c = hh + pp - 2.f*dot;
    cl[(size_t)gi*KC + j] = fmaxf(c, 0.f);
  }
}

// ---------------- K5a: stable counting sort by joint type (single block) ----------------
__global__ __launch_bounds__(512) void k_sort(const int* __restrict__ jt,
                                              int* order, int* tsv, int* offs) {
  __shared__ struct { unsigned cnt[512][NT]; int tot[NT]; int base[NT]; } sm;
  const int tid = threadIdx.x;
  const int CHS = 40;
  const int r0 = tid*CHS, r1 = min(NPT, r0 + CHS);
  for (int t = 0; t < NT; ++t) sm.cnt[tid][t] = 0;
  __syncthreads();
  for (int r = r0; r < r1; ++r) sm.cnt[tid][jt[r]]++;
  __syncthreads();
  if (tid < NT) {
    unsigned s = 0;
    for (int i = 0; i < 512; ++i) s += sm.cnt[i][tid];
    sm.tot[tid] = (int)s;
  }
  __syncthreads();
  if (tid == 0) {
    int acc = 0;
    for (int t = 0; t < NT; ++t) { sm.base[t] = acc; offs[t] = acc; acc += sm.tot[t]; }
    offs[NT] = acc;
  }
  __syncthreads();
  if (tid < NT) {
    unsigned run = (unsigned)sm.base[tid];
    for (int i = 0; i < 512; ++i) { unsigned c = sm.cnt[i][tid]; sm.cnt[i][tid] = run; run += c; }
  }
  __syncthreads();
  for (int r = r0; r < r1; ++r) {
    int t = jt[r];
    unsigned p = sm.cnt[tid][t]++;
    order[p] = r; tsv[p] = t;
  }
}

// ---------------- K5b: kmeans++ — 256 thr, 1 wave/SIMD, EVERYTHING in registers ----
// launch_bounds(256,1) -> 512-VGPR cap; px/py/dm[79] = 237 VGPR, no spill (m08: ok to ~450).
// Per step: dm update is pure VALU; only 79 coalesced Q loads + 1 pos[sel] pair touch memory.
#define KPT 79
__global__ __launch_bounds__(256, 1) void k_km(const float* __restrict__ pos,
                                               const int* __restrict__ i0p,
                                               const float* __restrict__ Q,
                                               float* centsg) {
  __shared__ float red[4];
  __shared__ int   redi[4];
  __shared__ int   bselsh;
  const int tid = threadIdx.x;
  const int lane = tid & 63, wv = tid >> 6;   // 4 waves
  float px[KPT], py[KPT], dm[KPT];
  const int i0 = *i0p;
  float cx = pos[2*i0], cy = pos[2*i0+1];
  if (tid == 0) { centsg[0] = cx; centsg[1] = cy; }
  #pragma unroll
  for (int u = 0; u < KPT; ++u) {
    int i = tid + (u << 8);
    bool v = i < NPT;
    float2 p = v ? *(const float2*)(pos + 2*i) : make_float2(0.f, 0.f);
    px[u] = p.x; py[u] = p.y;
    dm[u] = 3.4e38f;
  }
  for (int s = 1; s < KC; ++s) {
    const float* Qs = Q + (size_t)s*NPT;
    const float cc2 = cx*cx + cy*cy;
    float bsc = -3.4e38f; int bi = 0x7FFFFFFF;
    #pragma unroll
    for (int u = 0; u < KPT; ++u) {
      int i = tid + (u << 8);
      if (i < NPT) {
        float x = px[u], y = py[u];
        float d = fmaxf((x*x + y*y) + cc2 - 2.f*(x*cx + y*cy), 0.f);
        float nd = fminf(dm[u], d);
        dm[u] = nd;
        float sc = nd * Qs[i];
        if (sc > bsc || (sc == bsc && i < bi)) { bsc = sc; bi = i; }
      }
    }
    for (int o = 32; o; o >>= 1) {
      float osc = __shfl_xor(bsc, o, 64);
      int   oid = __shfl_xor(bi, o, 64);
      if (osc > bsc || (osc == bsc && oid < bi)) { bsc = osc; bi = oid; }
    }
    if (lane == 0) { red[wv] = bsc; redi[wv] = bi; }
    __syncthreads();
    if (tid == 0) {
      float bb = -3.4e38f; int bj = 0x7FFFFFFF;
      #pragma unroll
      for (int w = 0; w < 4; ++w) {
        float v2 = red[w]; int id2 = redi[w];
        if (v2 > bb || (v2 == bb && id2 < bj)) { bb = v2; bj = id2; }
      }
      bselsh = bj;
    }
    __syncthreads();
    const int sel = bselsh;
    cx = pos[2*sel]; cy = pos[2*sel+1];
    if (tid == 0) { centsg[2*s] = cx; centsg[2*s+1] = cy; }
    __syncthreads();
  }
}

// ---------------- K6: one Lloyd iteration (grid LGB=64) ----------------
__global__ __launch_bounds__(512) void k_lloyd(const float* __restrict__ pos,
                                               float* centsg, float* llp, int first) {
  const int b = blockIdx.x, tid = threadIdx.x, lane = tid & 63, wv = tid >> 6;
  __shared__ float cents[KC][2];
  __shared__ float comb[192];
  __shared__ float wpart[8][192];
  __shared__ int asg[CPB];
  if (tid < KC) { cents[tid][0] = centsg[2*tid]; cents[tid][1] = centsg[2*tid+1]; }
  __syncthreads();
  if (!first) {
    if (tid < 192) {
      float s = 0.f;
      for (int bb = 0; bb < LGB; ++bb) s += llp[bb*192 + tid];
      comb[tid] = s;
    }
    __syncthreads();
    if (tid < KC) {
      float cn = comb[128 + tid];
      if (cn > 0.f) {
        float dv = fmaxf(cn, 1.f);
        cents[tid][0] = comb[tid] / dv;
        cents[tid][1] = comb[64 + tid] / dv;
      }
    }
    __syncthreads();
    if (b == 0 && tid < KC) {   // benign same-value race
      centsg[2*tid] = cents[tid][0]; centsg[2*tid+1] = cents[tid][1];
    }
  }
  const int base = b*CPB;
  const int pcnt = max(0, min(NPT - base, CPB));
  if (tid < pcnt) {
    int i = base + tid;
    float x = pos[2*i], y = pos[2*i+1];
    float bd = 3.4e38f; int bj = 0;
    #pragma unroll 4
    for (int j = 0; j < KC; ++j) {
      float cx = cents[j][0], cy = cents[j][1];
      float d = (x*x + y*y) + (cx*cx + cy*cy) - 2.f*(x*cx + y*cy);
      d = fmaxf(d, 0.f);
      if (d < bd) { bd = d; bj = j; }
    }
    asg[tid] = bj;
  }
  __syncthreads();
  {
    int r0 = 40*wv, r1 = min(pcnt, r0 + 40);
    float sx = 0.f, sy = 0.f, cn = 0.f;
    for (int r = r0; r < r1; ++r) {
      int a = asg[r]; int i = base + r;
      float x = pos[2*i], y = pos[2*i+1];
      if (lane == a) { sx += x; sy += y; cn += 1.f; }
    }
    wpart[wv][lane] = sx; wpart[wv][64+lane] = sy; wpart[wv][128+lane] = cn;
  }
  __syncthreads();
  if (tid < 192) {
    float s = 0.f;
    #pragma unroll
    for (int w8 = 0; w8 < 8; ++w8) s += wpart[w8][tid];
    llp[b*192 + tid] = s;
  }
}

// ---------------- K7: final cent combine + cost build + run table (grid NBLK) ----------------
__global__ __launch_bounds__(512) void k_cb(const float* __restrict__ pos,
                                            const float* __restrict__ cl,
                                            const int* __restrict__ order,
                                            const int* __restrict__ tsv,
                                            const float* __restrict__ centsg,
                                            const float* __restrict__ llp,
                                            float* __restrict__ Ls, int* runT) {
  const int b = blockIdx.x, tid = threadIdx.x, lane = tid & 63, wv = tid >> 6;
  __shared__ float cents[KC][2];
  __shared__ float comb[192];
  if (tid < KC) { cents[tid][0] = centsg[2*tid]; cents[tid][1] = centsg[2*tid+1]; }
  __syncthreads();
  if (tid < 192) {
    float s = 0.f;
    for (int bb = 0; bb < LGB; ++bb) s += llp[bb*192 + tid];
    comb[tid] = s;
  }
  __syncthreads();
  if (tid < KC) {
    float cn = comb[128 + tid];
    if (cn > 0.f) {
      float dv = fmaxf(cn, 1.f);
      cents[tid][0] = comb[tid] / dv;
      cents[tid][1] = comb[64 + tid] / dv;
    }
  }
  if (tid == 0) {
    int nrun = 0, prev = -1;
    int rt[3] = {-1,-1,-1};
    for (int u = 0; u < RPB; ++u) {
      int t = tsv[b*RPB + u];
      if (t != prev) { if (nrun < 3) rt[nrun] = t; nrun++; prev = t; }
    }
    runT[b*3+0] = rt[0]; runT[b*3+1] = rt[1]; runT[b*3+2] = rt[2];
  }
  __syncthreads();
  #pragma unroll
  for (int k = 0; k < 10; ++k) {
    int ii = b*RPB + wv*10 + k;
    int od = order[ii];
    float x = pos[2*od], y = pos[2*od+1];
    float cx = cents[lane][0], cy = cents[lane][1];
    float cs = fmaxf((x*x + y*y) + (cx*cx + cy*cy) - 2.f*(x*cx + y*cy), 0.f);
    float cle = cl[(size_t)od*KC + lane];
    Ls[(size_t)ii*KC + lane] = -(cs + 0.5f*cle) / 0.05f;
  }
}

// ---------------- K8: one Sinkhorn iteration (grid NBLK) ----------------
template<int FIRST>
__global__ __launch_bounds__(512) void k_sink(const float* __restrict__ Ls,
                                              float* __restrict__ logu,
                                              const int* __restrict__ offs,
                                              const int* __restrict__ runT,
                                              const int* __restrict__ tsv,
                                              float* __restrict__ PMb, float* __restrict__ PSb,
                                              float* __restrict__ PLm, float* __restrict__ PLs) {
  const int b = blockIdx.x, tid = threadIdx.x, lane = tid & 63, wv = tid >> 6;
  __shared__ float lvs[3][64];
  __shared__ float wpm[8][2][64], wps[8][2][64];
  __shared__ int   wri[8][2];
  __shared__ float plmw[8], plsw[8];
  __shared__ float lvl_sh;
  const int rt0 = runT[b*3+0], rt1 = runT[b*3+1], rt2 = runT[b*3+2];

  if (!FIRST) {
    if (wv < 3) {
      int t = (wv == 0) ? rt0 : ((wv == 1) ? rt1 : rt2);
      if (t >= 0) {
        float m = -3.4e38f, s = 0.f;
        int bb0 = offs[t] / RPB, bb1 = (offs[t+1] - 1) / RPB;
        for (int bb = bb0; bb <= bb1; ++bb) {
          #pragma unroll
          for (int q = 0; q < 3; ++q) {
            if (runT[bb*3+q] == t)
              lse_merge(m, s, PMb[(bb*3+q)*64 + lane], PSb[(bb*3+q)*64 + lane]);
          }
        }
        lvs[wv][lane] = -(__logf(s) + m);
      }
    } else if (wv == 3) {
      float m = -3.4e38f, s = 0.f;
      for (int bb = lane; bb < NBLK; bb += 64) lse_merge(m, s, PLm[bb], PLs[bb]);
      for (int o = 32; o; o >>= 1) {
        float m2 = __shfl_xor(m, o, 64), s2 = __shfl_xor(s, o, 64);
        lse_merge(m, s, m2, s2);
      }
      if (lane == 0) lvl_sh = logf((float)(NPT - NSLOT)) - (__logf(s) + m);
    }
    __syncthreads();
  }
  const float lvl = FIRST ? 0.f : lvl_sh;

  float am0 = -3.4e38f, as0 = 0.f, am1 = -3.4e38f, as1 = 0.f;
  int r0i = -1, r1i = -1;
  float lm = -3.4e38f, lss = 0.f;
  #pragma unroll
  for (int k = 0; k < 10; ++k) {
    int ii = b*RPB + wv*10 + k;
    int t = tsv[ii];
    int rq = (t == rt0) ? 0 : ((t == rt1) ? 1 : 2);
    float lvv = FIRST ? 0.f : lvs[rq][lane];
    float Lv = Ls[(size_t)ii*KC + lane];
    float x = Lv + lvv;
    float m = x;
    for (int o = 32; o; o >>= 1) m = fmaxf(m, __shfl_xor(m, o, 64));
    m = fmaxf(m, lvl);
    float e = __expf(x - m);
    for (int o = 32; o; o >>= 1) e += __shfl_xor(e, o, 64);
    e += __expf(lvl - m);
    float lu = -(__logf(e) + m);
    if (lane == 0) logu[ii] = lu;
    float cv = Lv + lu;
    if (r0i < 0 || rq == r0i) { r0i = rq; lse_merge(am0, as0, cv, 1.0f); }
    else                      { r1i = rq; lse_merge(am1, as1, cv, 1.0f); }
    lse_merge(lm, lss, lu, 1.0f);
  }
  wpm[wv][0][lane] = am0; wps[wv][0][lane] = as0;
  wpm[wv][1][lane] = am1; wps[wv][1][lane] = as1;
  if (lane == 0) { wri[wv][0] = r0i; wri[wv][1] = r1i; plmw[wv] = lm; plsw[wv] = lss; }
  __syncthreads();
  if (wv < 3) {
    float m = -3.4e38f, s = 0.f;
    for (int w8 = 0; w8 < 8; ++w8) {
      if (wri[w8][0] == wv) lse_merge(m, s, wpm[w8][0][lane], wps[w8][0][lane]);
      if (wri[w8][1] == wv) lse_merge(m, s, wpm[w8][1][lane], wps[w8][1][lane]);
    }
    PMb[(b*3+wv)*64 + lane] = m; PSb[(b*3+wv)*64 + lane] = s;
  } else if (wv == 3 && lane == 0) {
    float m = -3.4e38f, s = 0.f;
    #pragma unroll
    for (int w8 = 0; w8 < 8; ++w8) lse_merge(m, s, plmw[w8], plsw[w8]);
    PLm[b] = m; PLs[b] = s;
  }
}

// ---------------- K9: final log_v + vals ----------------
__global__ __launch_bounds__(512) void k_fin(const float* __restrict__ Ls,
                                             const float* __restrict__ logu,
                                             const int* __restrict__ offs,
                                             const int* __restrict__ runT,
                                             const int* __restrict__ tsv,
                                             const int* __restrict__ order,
                                             const float* __restrict__ PMb,
                                             const float* __restrict__ PSb,
                                             float* __restrict__ vals) {
  const int b = blockIdx.x, tid = threadIdx.x, lane = tid & 63, wv = tid >> 6;
  __shared__ float lvs[3][64];
  const int rt0 = runT[b*3+0], rt1 = runT[b*3+1], rt2 = runT[b*3+2];
  if (wv < 3) {
    int t = (wv == 0) ? rt0 : ((wv == 1) ? rt1 : rt2);
    if (t >= 0) {
      float m = -3.4e38f, s = 0.f;
      int bb0 = offs[t] / RPB, bb1 = (offs[t+1] - 1) / RPB;
      for (int bb = bb0; bb <= bb1; ++bb) {
        #pragma unroll
        for (int q = 0; q < 3; ++q) {
          if (runT[bb*3+q] == t)
            lse_merge(m, s, PMb[(bb*3+q)*64 + lane], PSb[(bb*3+q)*64 + lane]);
        }
      }
      lvs[wv][lane] = -(__logf(s) + m);
    }
  }
  __syncthreads();
  #pragma unroll
  for (int k = 0; k < 10; ++k) {
    int ii = b*RPB + wv*10 + k;
    int t = tsv[ii];
    int rq = (t == rt0) ? 0 : ((t == rt1) ? 1 : 2);
    vals[(size_t)order[ii]*KC + lane] =
        __expf(Ls[(size_t)ii*KC + lane] + lvs[rq][lane] + logu[ii]);
  }
}

// ---------------- K10: expand vals into full T + logits = log(vals+1e-8) ----------------
__global__ __launch_bounds__(256) void k_T(float* __restrict__ vals,
                                           const int* __restrict__ jt,
                                           float* __restrict__ T) {
  __shared__ float v[KC];
  const int i = blockIdx.x;
  const int tid = threadIdx.x;
  if (tid < KC) v[tid] = vals[(size_t)i*KC + tid];
  __syncthreads();
  const int t = jt[i];
  for (int e = tid; e < NSLOT; e += 256) {
    int j = e / NT;
    int tt = e - j*NT;
    T[(size_t)i*NSLOT + e] = (tt == t) ? v[j] : 0.0f;
  }
  if (tid < KC) vals[(size_t)i*KC + tid] = logf(v[tid] + 1e-8f);
}

extern "C" void kernel_launch(void* const* d_in, const int* in_sizes, int n_in,
                              void* d_out, int out_size, void* d_ws, size_t ws_size,
                              hipStream_t stream) {
  const float* emb    = (const float*)d_in[0];
  const float* pos    = (const float*)d_in[1];
  const float* W1     = (const float*)d_in[2];
  const float* b1     = (const float*)d_in[3];
  const float* protos = (const float*)d_in[4];
  const int*   jt     = (const int*)d_in[5];

  float* out  = (float*)d_out;
  float* vals = out;
  float* T    = out + (size_t)NPT*KC;
  float* TS   = T;

  unsigned* sub = (unsigned*)(TS + OFF_SUB);
  int* i0p    = (int*)(TS + OFF_I0);
  int* order  = (int*)(TS + OFF_ORDER);
  int* tsv    = (int*)(TS + OFF_TSV);
  int* offs   = (int*)(TS + OFF_OFFS);
  int* runT   = (int*)(TS + OFF_RUNT);
  float* centsg = TS + OFF_CENTS;
  float* llp  = TS + OFF_LLP;
  float* Ls   = TS + OFF_LS;
  float* logu = TS + OFF_LOGU;
  float* PMb  = TS + OFF_PMB;
  float* PSb  = TS + OFF_PSB;
  float* PLm  = TS + OFF_PLM;
  float* PLs  = TS + OFF_PLS;

  hipLaunchKernelGGL(k_keys, dim3(1), dim3(64), 0, stream, sub, i0p);
  hipLaunchKernelGGL(k_gumbel, dim3((NPT + 255)/256, KC - 1), dim3(256), 0, stream,
                     sub, TS + OFF_Q);
  hipLaunchKernelGGL(k_gemm, dim3((NPT + 63)/64), dim3(256), 0, stream,
                     emb, W1, b1, TS + OFF_H);
  hipLaunchKernelGGL(k_cl, dim3((NPT + 3)/4), dim3(256), 0, stream,
                     TS + OFF_H, protos, TS + OFF_CL);
  hipLaunchKernelGGL(k_sort, dim3(1), dim3(512), 0, stream, jt, order, tsv, offs);
  hipLaunchKernelGGL(k_km, dim3(1), dim3(256), 0, stream,
                     pos, i0p, TS + OFF_Q, centsg);

  for (int it = 0; it < 10; ++it)
    hipLaunchKernelGGL(k_lloyd, dim3(LGB), dim3(512), 0, stream,
                       pos, centsg, llp, (it == 0) ? 1 : 0);

  hipLaunchKernelGGL(k_cb, dim3(NBLK), dim3(512), 0, stream,
                     pos, TS + OFF_CL, order, tsv, centsg, llp, Ls, runT);

  hipLaunchKernelGGL(k_sink<1>, dim3(NBLK), dim3(512), 0, stream,
                     Ls, logu, offs, runT, tsv, PMb, PSb, PLm, PLs);
  for (int it = 1; it < SINK_IT; ++it)
    hipLaunchKernelGGL(k_sink<0>, dim3(NBLK), dim3(512), 0, stream,
                       Ls, logu, offs, runT, tsv, PMb, PSb, PLm, PLs);

  hipLaunchKernelGGL(k_fin, dim3(NBLK), dim3(512), 0, stream,
                     Ls, logu, offs, runT, tsv, order, PMb, PSb, vals);

  hipLaunchKernelGGL(k_T, dim3(NPT), dim3(256), 0, stream, vals, jt, T);
}

// Round 14
// 1682.290 us; speedup vs baseline: 1.6491x; 1.6491x over previous
//
#include <hip/hip_runtime.h>

#define NPT 20000
#define DIMK 256
#define HD 128
#define KC 64
#define NT 17
#define NSLOT (KC*NT)          // 1088
#define SINK_IT 50
#define NBLK 250               // sinkhorn/cb blocks: 80 rows each
#define RPB 80
#define LGB 64                 // lloyd blocks
#define CPB 313                // lloyd points per block (64*313 >= 20000)
#define GEB 313                // gemm+cl blocks (64 rows each)
#define FBLK (1 + GEB + 1)     // km + gemm/cl + sort

// ---- scratch offsets (floats) inside the T region of d_out ----
#define OFF_H     0
#define OFF_CL    (NPT*HD)                   // 2,560,000
#define OFF_Q     (OFF_CL + NPT*KC)
#define OFF_LS    (OFF_Q + KC*NPT)
#define OFF_LOGU  (OFF_LS + NPT*KC)
#define OFF_ORDER (OFF_LOGU + NPT)
#define OFF_TSV   (OFF_ORDER + NPT)
#define OFF_OFFS  (OFF_TSV + NPT)            // 32 ints
#define OFF_CENTS (OFF_OFFS + 32)            // 128 f
#define OFF_I0    (OFF_CENTS + 128)
#define OFF_SUB   (OFF_I0 + 32)
#define OFF_LLP   (OFF_SUB + 128)            // LGB*192
#define OFF_PMB   (OFF_LLP + LGB*192)        // NBLK*3*64 = 48000
#define OFF_PSB   (OFF_PMB + NBLK*3*64)
#define OFF_RUNT  (OFF_PSB + NBLK*3*64)      // 750 ints -> 768
#define OFF_PLM   (OFF_RUNT + 768)           // 256
#define OFF_PLS   (OFF_PLM + 256)            // 256
// end ~= 6.53M floats << 21.76M floats of T region

__device__ __forceinline__ void tf2x32(unsigned k0, unsigned k1,
                                       unsigned x0, unsigned x1,
                                       unsigned& o0, unsigned& o1) {
  unsigned ks0 = k0, ks1 = k1, ks2 = k0 ^ k1 ^ 0x1BD11BDAu;
  x0 += ks0; x1 += ks1;
  const int rot[2][4] = {{13,15,26,6},{17,29,16,24}};
  unsigned ks[3] = {ks0, ks1, ks2};
  #pragma unroll
  for (int i = 0; i < 5; ++i) {
    #pragma unroll
    for (int r = 0; r < 4; ++r) {
      int rr = rot[i & 1][r];
      x0 += x1;
      x1 = (x1 << rr) | (x1 >> (32 - rr));
      x1 ^= x0;
    }
    x0 += ks[(i+1)%3];
    x1 += ks[(i+2)%3] + (unsigned)(i+1);
  }
  o0 = x0; o1 = x1;
}

__device__ __forceinline__ void lse_merge(float& m, float& s, float m2, float s2) {
  float mn = fmaxf(m, m2);
  s = s*__expf(m - mn) + s2*__expf(m2 - mn);
  m = mn;
}

// ---------------- K1: key chain + randint i0 (verified R5) ----------------
__global__ void k_keys(unsigned* sub, int* i0p) {
  if (threadIdx.x != 0 || blockIdx.x != 0) return;
  unsigned key0 = 0u, key1 = 42u;
  unsigned c0, c1, s0, s1;
  tf2x32(key0, key1, 0u, 0u, c0, c1);
  tf2x32(key0, key1, 0u, 1u, s0, s1);
  key0 = c0; key1 = c1;
  unsigned k1a, k1b, k2a, k2b;
  tf2x32(s0, s1, 0u, 0u, k1a, k1b);
  tf2x32(s0, s1, 0u, 1u, k2a, k2b);
  unsigned h0, h1, l0, l1;
  tf2x32(k1a, k1b, 0u, 0u, h0, h1);
  tf2x32(k2a, k2b, 0u, 0u, l0, l1);
  unsigned hb = h0 ^ h1, lb = l0 ^ l1;
  unsigned span = 20000u;
  unsigned m1 = 65536u % span;
  unsigned mult = (unsigned)(((unsigned long long)m1 * m1) % span);  // 7296
  unsigned off32 = (hb % span) * mult + (lb % span);
  *i0p = (int)(off32 % span);
  sub[0] = 0u; sub[1] = 0u;
  for (int i = 1; i < KC; ++i) {
    tf2x32(key0, key1, 0u, 0u, c0, c1);
    tf2x32(key0, key1, 0u, 1u, s0, s1);
    key0 = c0; key1 = c1;
    sub[2*i] = s0; sub[2*i+1] = s1;
  }
}

// ---------------- K2: Q[step][i] = exp(gumbel) = -1/log(u) ----------------
__global__ __launch_bounds__(256) void k_gumbel(const unsigned* __restrict__ sub,
                                                float* __restrict__ Q) {
  int s = blockIdx.y + 1;
  int i = blockIdx.x * 256 + threadIdx.x;
  if (i >= NPT) return;
  unsigned o0, o1;
  tf2x32(sub[2*s], sub[2*s+1], 0u, (unsigned)i, o0, o1);
  unsigned bits = o0 ^ o1;
  unsigned fb = (bits >> 9) | 0x3f800000u;
  float u = __uint_as_float(fb) - 1.0f;
  if (u == 0.0f) u = 1.17549435e-38f;
  Q[(size_t)s*NPT + i] = -1.0f / logf(u);
}

// ---------------- K3: fused front — km (blk 0) | gemm+cl (blks 1..313) | sort (blk 314) ----
union FrontSM {
  struct { float red[16]; int redi[16]; int bsel; } km;
  struct { float As[64][64]; float Bs[64][HD]; } ge;       // 48KB (gemm phase)
  struct { float ht[64][HD]; float ps[64][HD]; } c2;       // 64KB (cl phase; aliases ge)
  struct { unsigned cnt[512][NT]; int tot[NT]; int base[NT]; } srt;
};

#define KPT 20
__global__ __launch_bounds__(1024) void k_front(const float* __restrict__ pos,
                                                const int* __restrict__ i0p,
                                                const float* __restrict__ Q,
                                                float* centsg,
                                                const float* __restrict__ emb,
                                                const float* __restrict__ W1,
                                                const float* __restrict__ b1,
                                                const float* __restrict__ protos,
                                                float* __restrict__ cl,
                                                const int* __restrict__ jt,
                                                int* order, int* tsv, int* offs) {
  __shared__ FrontSM sm;
  const int b = blockIdx.x, tid = threadIdx.x;
  const int lane = tid & 63, wv = tid >> 6;

  if (b == 0) {
    // ===== kmeans++ (R12 code, verified 0.125) =====
    float dm[KPT];
    const int i0 = *i0p;
    float cx = pos[2*i0], cy = pos[2*i0+1];
    if (tid == 0) { centsg[0] = cx; centsg[1] = cy; }
    #pragma unroll
    for (int u = 0; u < KPT; ++u) dm[u] = 3.4e38f;
    for (int s = 1; s < KC; ++s) {
      const float* Qs = Q + (size_t)s*NPT;
      const float cc2 = cx*cx + cy*cy;
      float bsc = -3.4e38f; int bi = 0x7FFFFFFF;
      #pragma unroll
      for (int u = 0; u < KPT; ++u) {
        int i = tid + (u << 10);
        if (i < NPT) {
          float2 p = *(const float2*)(pos + 2*i);
          float d = fmaxf((p.x*p.x + p.y*p.y) + cc2 - 2.f*(p.x*cx + p.y*cy), 0.f);
          float nd = fminf(dm[u], d);
          dm[u] = nd;
          float sc = nd * Qs[i];
          if (sc > bsc || (sc == bsc && i < bi)) { bsc = sc; bi = i; }
        }
      }
      for (int o = 32; o; o >>= 1) {
        float osc = __shfl_xor(bsc, o, 64);
        int   oid = __shfl_xor(bi, o, 64);
        if (osc > bsc || (osc == bsc && oid < bi)) { bsc = osc; bi = oid; }
      }
      if (lane == 0) { sm.km.red[wv] = bsc; sm.km.redi[wv] = bi; }
      __syncthreads();
      if (tid == 0) {
        float bb = -3.4e38f; int bj = 0x7FFFFFFF;
        #pragma unroll
        for (int w = 0; w < 16; ++w) {
          float v2 = sm.km.red[w]; int id2 = sm.km.redi[w];
          if (v2 > bb || (v2 == bb && id2 < bj)) { bb = v2; bj = id2; }
        }
        sm.km.bsel = bj;
      }
      __syncthreads();
      const int sel = sm.km.bsel;
      cx = pos[2*sel]; cy = pos[2*sel+1];
      if (tid == 0) { centsg[2*s] = cx; centsg[2*s+1] = cy; }
      __syncthreads();
    }
  } else if (b <= GEB) {
    // ===== gemm tile (threads 0-255) + cl (all 1024), h stays in LDS =====
    const int m0 = (b - 1) * 64;
    const int tx = tid & 31, ty = (tid >> 5) & 7;
    float acc[8][4];
    #pragma unroll
    for (int a = 0; a < 8; ++a)
      #pragma unroll
      for (int c = 0; c < 4; ++c) acc[a][c] = 0.f;

    for (int kc = 0; kc < DIMK; kc += 64) {
      if (tid < 256) {
        #pragma unroll
        for (int it = 0; it < 4; ++it) {
          int f = it*256 + tid;
          int r = f >> 4;
          int kk = (f & 15) << 2;
          float4 v = make_float4(0.f,0.f,0.f,0.f);
          if (m0 + r < NPT)
            v = *(const float4*)(emb + (size_t)(m0 + r)*DIMK + kc + kk);
          sm.ge.As[kk+0][r] = v.x; sm.ge.As[kk+1][r] = v.y;
          sm.ge.As[kk+2][r] = v.z; sm.ge.As[kk+3][r] = v.w;
        }
        #pragma unroll
        for (int it = 0; it < 8; ++it) {
          int f = it*256 + tid;
          int kk = f >> 5;
          int cc = (f & 31) << 2;
          *(float4*)&sm.ge.Bs[kk][cc] = *(const float4*)(W1 + (size_t)(kc + kk)*HD + cc);
        }
      }
      __syncthreads();
      if (tid < 256) {
        #pragma unroll 8
        for (int kk = 0; kk < 64; ++kk) {
          float4 a0 = *(float4*)&sm.ge.As[kk][ty*8];
          float4 a1 = *(float4*)&sm.ge.As[kk][ty*8+4];
          float4 bb = *(float4*)&sm.ge.Bs[kk][tx*4];
          float av[8] = {a0.x,a0.y,a0.z,a0.w,a1.x,a1.y,a1.z,a1.w};
          float bv[4] = {bb.x,bb.y,bb.z,bb.w};
          #pragma unroll
          for (int a = 0; a < 8; ++a)
            #pragma unroll
            for (int c = 0; c < 4; ++c) acc[a][c] += av[a]*bv[c];
        }
      }
      __syncthreads();
    }
    // write h tile (selu) into LDS (aliases As/Bs; all reads completed)
    if (tid < 256) {
      const float SC = 1.0507009873554805f, AL = 1.6732632423543772f;
      #pragma unroll
      for (int a = 0; a < 8; ++a) {
        int r = ty*8 + a;
        #pragma unroll
        for (int c = 0; c < 4; ++c) {
          float x = acc[a][c] + b1[tx*4 + c];
          float v = (x > 0.f) ? x : AL * expm1f(x);
          sm.c2.ht[r][tx*4 + c] = SC * v;
        }
      }
    }
    // load protos (all threads)
    for (int f = tid; f < KC*HD; f += 1024)
      sm.c2.ps[f >> 7][f & 127] = protos[f];
    __syncthreads();
    // cl: 4096 (row,proto) pairs, 4 per thread; same per-pair FP order as k_cl
    #pragma unroll
    for (int q = 0; q < 4; ++q) {
      int p = tid + (q << 10);
      int r = p >> 6, j = p & 63;
      int gi = m0 + r;
      if (gi < NPT) {
        float dot = 0.f, hh = 0.f, pp = 0.f;
        #pragma unroll 8
        for (int d = 0; d < HD; ++d) {
          float a = sm.c2.ht[r][d], bb = sm.c2.ps[j][d];
          dot += a*bb; hh += a*a; pp += bb*bb;
        }
        float c = hh + pp - 2.f*dot;
        cl[(size_t)gi*KC + j] = fmaxf(c, 0.f);
      }
    }
  } else {
    // ===== counting sort (threads 0-511 active; all hit barriers) =====
    const int CHS = 40;
    const int r0 = tid*CHS, r1 = min(NPT, r0 + CHS);
    if (tid < 512) for (int t = 0; t < NT; ++t) sm.srt.cnt[tid][t] = 0;
    __syncthreads();
    if (tid < 512) for (int r = r0; r < r1; ++r) sm.srt.cnt[tid][jt[r]]++;
    __syncthreads();
    if (tid < NT) {
      unsigned s = 0;
      for (int i = 0; i < 512; ++i) s += sm.srt.cnt[i][tid];
      sm.srt.tot[tid] = (int)s;
    }
    __syncthreads();
    if (tid == 0) {
      int acc = 0;
      for (int t = 0; t < NT; ++t) { sm.srt.base[t] = acc; offs[t] = acc; acc += sm.srt.tot[t]; }
      offs[NT] = acc;
    }
    __syncthreads();
    if (tid < NT) {
      unsigned run = (unsigned)sm.srt.base[tid];
      for (int i = 0; i < 512; ++i) { unsigned c = sm.srt.cnt[i][tid]; sm.srt.cnt[i][tid] = run; run += c; }
    }
    __syncthreads();
    if (tid < 512) {
      for (int r = r0; r < r1; ++r) {
        int t = jt[r];
        unsigned p = sm.srt.cnt[tid][t]++;
        order[p] = r; tsv[p] = t;
      }
    }
  }
}

// ---------------- K6: one Lloyd iteration (grid LGB=64) ----------------
__global__ __launch_bounds__(512) void k_lloyd(const float* __restrict__ pos,
                                               float* centsg, float* llp, int first) {
  const int b = blockIdx.x, tid = threadIdx.x, lane = tid & 63, wv = tid >> 6;
  __shared__ float cents[KC][2];
  __shared__ float comb[192];
  __shared__ float wpart[8][192];
  __shared__ int asg[CPB];
  if (tid < KC) { cents[tid][0] = centsg[2*tid]; cents[tid][1] = centsg[2*tid+1]; }
  __syncthreads();
  if (!first) {
    if (tid < 192) {
      float s = 0.f;
      for (int bb = 0; bb < LGB; ++bb) s += llp[bb*192 + tid];
      comb[tid] = s;
    }
    __syncthreads();
    if (tid < KC) {
      float cn = comb[128 + tid];
      if (cn > 0.f) {
        float dv = fmaxf(cn, 1.f);
        cents[tid][0] = comb[tid] / dv;
        cents[tid][1] = comb[64 + tid] / dv;
      }
    }
    __syncthreads();
    if (b == 0 && tid < KC) {   // benign same-value race
      centsg[2*tid] = cents[tid][0]; centsg[2*tid+1] = cents[tid][1];
    }
  }
  const int base = b*CPB;
  const int pcnt = max(0, min(NPT - base, CPB));
  if (tid < pcnt) {
    int i = base + tid;
    float x = pos[2*i], y = pos[2*i+1];
    float bd = 3.4e38f; int bj = 0;
    #pragma unroll 4
    for (int j = 0; j < KC; ++j) {
      float cx = cents[j][0], cy = cents[j][1];
      float d = (x*x + y*y) + (cx*cx + cy*cy) - 2.f*(x*cx + y*cy);
      d = fmaxf(d, 0.f);
      if (d < bd) { bd = d; bj = j; }
    }
    asg[tid] = bj;
  }
  __syncthreads();
  {
    int r0 = 40*wv, r1 = min(pcnt, r0 + 40);
    float sx = 0.f, sy = 0.f, cn = 0.f;
    for (int r = r0; r < r1; ++r) {
      int a = asg[r]; int i = base + r;
      float x = pos[2*i], y = pos[2*i+1];
      if (lane == a) { sx += x; sy += y; cn += 1.f; }
    }
    wpart[wv][lane] = sx; wpart[wv][64+lane] = sy; wpart[wv][128+lane] = cn;
  }
  __syncthreads();
  if (tid < 192) {
    float s = 0.f;
    #pragma unroll
    for (int w8 = 0; w8 < 8; ++w8) s += wpart[w8][tid];
    llp[b*192 + tid] = s;
  }
}

// ---------------- K7: final cent combine + cost build + run table (grid NBLK) ----------------
__global__ __launch_bounds__(512) void k_cb(const float* __restrict__ pos,
                                            const float* __restrict__ cl,
                                            const int* __restrict__ order,
                                            const int* __restrict__ tsv,
                                            const float* __restrict__ centsg,
                                            const float* __restrict__ llp,
                                            float* __restrict__ Ls, int* runT) {
  const int b = blockIdx.x, tid = threadIdx.x, lane = tid & 63, wv = tid >> 6;
  __shared__ float cents[KC][2];
  __shared__ float comb[192];
  if (tid < KC) { cents[tid][0] = centsg[2*tid]; cents[tid][1] = centsg[2*tid+1]; }
  __syncthreads();
  if (tid < 192) {
    float s = 0.f;
    for (int bb = 0; bb < LGB; ++bb) s += llp[bb*192 + tid];
    comb[tid] = s;
  }
  __syncthreads();
  if (tid < KC) {
    float cn = comb[128 + tid];
    if (cn > 0.f) {
      float dv = fmaxf(cn, 1.f);
      cents[tid][0] = comb[tid] / dv;
      cents[tid][1] = comb[64 + tid] / dv;
    }
  }
  if (tid == 0) {
    int nrun = 0, prev = -1;
    int rt[3] = {-1,-1,-1};
    for (int u = 0; u < RPB; ++u) {
      int t = tsv[b*RPB + u];
      if (t != prev) { if (nrun < 3) rt[nrun] = t; nrun++; prev = t; }
    }
    runT[b*3+0] = rt[0]; runT[b*3+1] = rt[1]; runT[b*3+2] = rt[2];
  }
  __syncthreads();
  #pragma unroll
  for (int k = 0; k < 10; ++k) {
    int ii = b*RPB + wv*10 + k;
    int od = order[ii];
    float x = pos[2*od], y = pos[2*od+1];
    float cx = cents[lane][0], cy = cents[lane][1];
    float cs = fmaxf((x*x + y*y) + (cx*cx + cy*cy) - 2.f*(x*cx + y*cy), 0.f);
    float cle = cl[(size_t)od*KC + lane];
    Ls[(size_t)ii*KC + lane] = -(cs + 0.5f*cle) / 0.05f;
  }
}

// ---------------- K8: one Sinkhorn iteration (grid NBLK) ----------------
template<int FIRST>
__global__ __launch_bounds__(512) void k_sink(const float* __restrict__ Ls,
                                              float* __restrict__ logu,
                                              const int* __restrict__ offs,
                                              const int* __restrict__ runT,
                                              const int* __restrict__ tsv,
                                              float* __restrict__ PMb, float* __restrict__ PSb,
                                              float* __restrict__ PLm, float* __restrict__ PLs) {
  const int b = blockIdx.x, tid = threadIdx.x, lane = tid & 63, wv = tid >> 6;
  __shared__ float lvs[3][64];
  __shared__ float wpm[8][2][64], wps[8][2][64];
  __shared__ int   wri[8][2];
  __shared__ float plmw[8], plsw[8];
  __shared__ float lvl_sh;
  const int rt0 = runT[b*3+0], rt1 = runT[b*3+1], rt2 = runT[b*3+2];

  if (!FIRST) {
    if (wv < 3) {
      int t = (wv == 0) ? rt0 : ((wv == 1) ? rt1 : rt2);
      if (t >= 0) {
        float m = -3.4e38f, s = 0.f;
        int bb0 = offs[t] / RPB, bb1 = (offs[t+1] - 1) / RPB;
        for (int bb = bb0; bb <= bb1; ++bb) {
          #pragma unroll
          for (int q = 0; q < 3; ++q) {
            if (runT[bb*3+q] == t)
              lse_merge(m, s, PMb[(bb*3+q)*64 + lane], PSb[(bb*3+q)*64 + lane]);
          }
        }
        lvs[wv][lane] = -(__logf(s) + m);
      }
    } else if (wv == 3) {
      float m = -3.4e38f, s = 0.f;
      for (int bb = lane; bb < NBLK; bb += 64) lse_merge(m, s, PLm[bb], PLs[bb]);
      for (int o = 32; o; o >>= 1) {
        float m2 = __shfl_xor(m, o, 64), s2 = __shfl_xor(s, o, 64);
        lse_merge(m, s, m2, s2);
      }
      if (lane == 0) lvl_sh = logf((float)(NPT - NSLOT)) - (__logf(s) + m);
    }
    __syncthreads();
  }
  const float lvl = FIRST ? 0.f : lvl_sh;

  float am0 = -3.4e38f, as0 = 0.f, am1 = -3.4e38f, as1 = 0.f;
  int r0i = -1, r1i = -1;
  float lm = -3.4e38f, lss = 0.f;
  #pragma unroll
  for (int k = 0; k < 10; ++k) {
    int ii = b*RPB + wv*10 + k;
    int t = tsv[ii];
    int rq = (t == rt0) ? 0 : ((t == rt1) ? 1 : 2);
    float lvv = FIRST ? 0.f : lvs[rq][lane];
    float Lv = Ls[(size_t)ii*KC + lane];
    float x = Lv + lvv;
    float m = x;
    for (int o = 32; o; o >>= 1) m = fmaxf(m, __shfl_xor(m, o, 64));
    m = fmaxf(m, lvl);
    float e = __expf(x - m);
    for (int o = 32; o; o >>= 1) e += __shfl_xor(e, o, 64);
    e += __expf(lvl - m);
    float lu = -(__logf(e) + m);
    if (lane == 0) logu[ii] = lu;
    float cv = Lv + lu;
    if (r0i < 0 || rq == r0i) { r0i = rq; lse_merge(am0, as0, cv, 1.0f); }
    else                      { r1i = rq; lse_merge(am1, as1, cv, 1.0f); }
    lse_merge(lm, lss, lu, 1.0f);
  }
  wpm[wv][0][lane] = am0; wps[wv][0][lane] = as0;
  wpm[wv][1][lane] = am1; wps[wv][1][lane] = as1;
  if (lane == 0) { wri[wv][0] = r0i; wri[wv][1] = r1i; plmw[wv] = lm; plsw[wv] = lss; }
  __syncthreads();
  if (wv < 3) {
    float m = -3.4e38f, s = 0.f;
    for (int w8 = 0; w8 < 8; ++w8) {
      if (wri[w8][0] == wv) lse_merge(m, s, wpm[w8][0][lane], wps[w8][0][lane]);
      if (wri[w8][1] == wv) lse_merge(m, s, wpm[w8][1][lane], wps[w8][1][lane]);
    }
    PMb[(b*3+wv)*64 + lane] = m; PSb[(b*3+wv)*64 + lane] = s;
  } else if (wv == 3 && lane == 0) {
    float m = -3.4e38f, s = 0.f;
    #pragma unroll
    for (int w8 = 0; w8 < 8; ++w8) lse_merge(m, s, plmw[w8], plsw[w8]);
    PLm[b] = m; PLs[b] = s;
  }
}

// ---------------- K9: final log_v + vals ----------------
__global__ __launch_bounds__(512) void k_fin(const float* __restrict__ Ls,
                                             const float* __restrict__ logu,
                                             const int* __restrict__ offs,
                                             const int* __restrict__ runT,
                                             const int* __restrict__ tsv,
                                             const int* __restrict__ order,
                                             const float* __restrict__ PMb,
                                             const float* __restrict__ PSb,
                                             float* __restrict__ vals) {
  const int b = blockIdx.x, tid = threadIdx.x, lane = tid & 63, wv = tid >> 6;
  __shared__ float lvs[3][64];
  const int rt0 = runT[b*3+0], rt1 = runT[b*3+1], rt2 = runT[b*3+2];
  if (wv < 3) {
    int t = (wv == 0) ? rt0 : ((wv == 1) ? rt1 : rt2);
    if (t >= 0) {
      float m = -3.4e38f, s = 0.f;
      int bb0 = offs[t] / RPB, bb1 = (offs[t+1] - 1) / RPB;
      for (int bb = bb0; bb <= bb1; ++bb) {
        #pragma unroll
        for (int q = 0; q < 3; ++q) {
          if (runT[bb*3+q] == t)
            lse_merge(m, s, PMb[(bb*3+q)*64 + lane], PSb[(bb*3+q)*64 + lane]);
        }
      }
      lvs[wv][lane] = -(__logf(s) + m);
    }
  }
  __syncthreads();
  #pragma unroll
  for (int k = 0; k < 10; ++k) {
    int ii = b*RPB + wv*10 + k;
    int t = tsv[ii];
    int rq = (t == rt0) ? 0 : ((t == rt1) ? 1 : 2);
    vals[(size_t)order[ii]*KC + lane] =
        __expf(Ls[(size_t)ii*KC + lane] + lvs[rq][lane] + logu[ii]);
  }
}

// ---------------- K10: expand vals into full T + logits = log(vals+1e-8) ----------------
__global__ __launch_bounds__(256) void k_T(float* __restrict__ vals,
                                           const int* __restrict__ jt,
                                           float* __restrict__ T) {
  __shared__ float v[KC];
  const int i = blockIdx.x;
  const int tid = threadIdx.x;
  if (tid < KC) v[tid] = vals[(size_t)i*KC + tid];
  __syncthreads();
  const int t = jt[i];
  for (int e = tid; e < NSLOT; e += 256) {
    int j = e / NT;
    int tt = e - j*NT;
    T[(size_t)i*NSLOT + e] = (tt == t) ? v[j] : 0.0f;
  }
  if (tid < KC) vals[(size_t)i*KC + tid] = logf(v[tid] + 1e-8f);
}

extern "C" void kernel_launch(void* const* d_in, const int* in_sizes, int n_in,
                              void* d_out, int out_size, void* d_ws, size_t ws_size,
                              hipStream_t stream) {
  const float* emb    = (const float*)d_in[0];
  const float* pos    = (const float*)d_in[1];
  const float* W1     = (const float*)d_in[2];
  const float* b1     = (const float*)d_in[3];
  const float* protos = (const float*)d_in[4];
  const int*   jt     = (const int*)d_in[5];

  float* out  = (float*)d_out;
  float* vals = out;
  float* T    = out + (size_t)NPT*KC;
  float* TS   = T;

  unsigned* sub = (unsigned*)(TS + OFF_SUB);
  int* i0p    = (int*)(TS + OFF_I0);
  int* order  = (int*)(TS + OFF_ORDER);
  int* tsv    = (int*)(TS + OFF_TSV);
  int* offs   = (int*)(TS + OFF_OFFS);
  int* runT   = (int*)(TS + OFF_RUNT);
  float* centsg = TS + OFF_CENTS;
  float* llp  = TS + OFF_LLP;
  float* Ls   = TS + OFF_LS;
  float* logu = TS + OFF_LOGU;
  float* PMb  = TS + OFF_PMB;
  float* PSb  = TS + OFF_PSB;
  float* PLm  = TS + OFF_PLM;
  float* PLs  = TS + OFF_PLS;

  hipLaunchKernelGGL(k_keys, dim3(1), dim3(64), 0, stream, sub, i0p);
  hipLaunchKernelGGL(k_gumbel, dim3((NPT + 255)/256, KC - 1), dim3(256), 0, stream,
                     sub, TS + OFF_Q);
  hipLaunchKernelGGL(k_front, dim3(FBLK), dim3(1024), 0, stream,
                     pos, i0p, TS + OFF_Q, centsg,
                     emb, W1, b1, protos, TS + OFF_CL,
                     jt, order, tsv, offs);

  for (int it = 0; it < 10; ++it)
    hipLaunchKernelGGL(k_lloyd, dim3(LGB), dim3(512), 0, stream,
                       pos, centsg, llp, (it == 0) ? 1 : 0);

  hipLaunchKernelGGL(k_cb, dim3(NBLK), dim3(512), 0, stream,
                     pos, TS + OFF_CL, order, tsv, centsg, llp, Ls, runT);

  hipLaunchKernelGGL(k_sink<1>, dim3(NBLK), dim3(512), 0, stream,
                     Ls, logu, offs, runT, tsv, PMb, PSb, PLm, PLs);
  for (int it = 1; it < SINK_IT; ++it)
    hipLaunchKernelGGL(k_sink<0>, dim3(NBLK), dim3(512), 0, stream,
                       Ls, logu, offs, runT, tsv, PMb, PSb, PLm, PLs);

  hipLaunchKernelGGL(k_fin, dim3(NBLK), dim3(512), 0, stream,
                     Ls, logu, offs, runT, tsv, order, PMb, PSb, vals);

  hipLaunchKernelGGL(k_T, dim3(NPT), dim3(256), 0, stream, vals, jt, T);
}

// Round 15
// 1680.406 us; speedup vs baseline: 1.6509x; 1.0011x over previous
//
#include <hip/hip_runtime.h>

#define NPT 20000
#define DIMK 256
#define HD 128
#define KC 64
#define NT 17
#define NSLOT (KC*NT)          // 1088
#define SINK_IT 50
#define NBLK 250               // sinkhorn/cb blocks: 80 rows each
#define RPB 80
#define LGB 64                 // lloyd blocks
#define CPB 313                // lloyd points per block (64*313 >= 20000)
#define GEB 313                // gemm+cl blocks (64 rows each)
#define FBLK (1 + GEB + 1)     // km + gemm/cl + sort

// ---- scratch offsets (floats) inside the T region of d_out ----
#define OFF_H     0
#define OFF_CL    (NPT*HD)                   // 2,560,000
#define OFF_Q     (OFF_CL + NPT*KC)
#define OFF_LS    (OFF_Q + KC*NPT)
#define OFF_LOGU  (OFF_LS + NPT*KC)
#define OFF_ORDER (OFF_LOGU + NPT)
#define OFF_TSV   (OFF_ORDER + NPT)
#define OFF_OFFS  (OFF_TSV + NPT)            // 32 ints
#define OFF_CENTS (OFF_OFFS + 32)            // 128 f
#define OFF_I0    (OFF_CENTS + 128)
#define OFF_SUB   (OFF_I0 + 32)
#define OFF_LLP   (OFF_SUB + 128)            // LGB*192
#define OFF_PMB   (OFF_LLP + LGB*192)        // NBLK*3*64 = 48000
#define OFF_PSB   (OFF_PMB + NBLK*3*64)
#define OFF_RUNT  (OFF_PSB + NBLK*3*64)      // 750 ints -> 768
#define OFF_PLM   (OFF_RUNT + 768)           // 256
#define OFF_PLS   (OFF_PLM + 256)            // 256
// end ~= 6.53M floats << 21.76M floats of T region

__device__ __forceinline__ void tf2x32(unsigned k0, unsigned k1,
                                       unsigned x0, unsigned x1,
                                       unsigned& o0, unsigned& o1) {
  unsigned ks0 = k0, ks1 = k1, ks2 = k0 ^ k1 ^ 0x1BD11BDAu;
  x0 += ks0; x1 += ks1;
  const int rot[2][4] = {{13,15,26,6},{17,29,16,24}};
  unsigned ks[3] = {ks0, ks1, ks2};
  #pragma unroll
  for (int i = 0; i < 5; ++i) {
    #pragma unroll
    for (int r = 0; r < 4; ++r) {
      int rr = rot[i & 1][r];
      x0 += x1;
      x1 = (x1 << rr) | (x1 >> (32 - rr));
      x1 ^= x0;
    }
    x0 += ks[(i+1)%3];
    x1 += ks[(i+2)%3] + (unsigned)(i+1);
  }
  o0 = x0; o1 = x1;
}

__device__ __forceinline__ void lse_merge(float& m, float& s, float m2, float s2) {
  float mn = fmaxf(m, m2);
  s = s*__expf(m - mn) + s2*__expf(m2 - mn);
  m = mn;
}

// ---------------- K1: key chain + randint i0 (verified R5) ----------------
__global__ void k_keys(unsigned* sub, int* i0p) {
  if (threadIdx.x != 0 || blockIdx.x != 0) return;
  unsigned key0 = 0u, key1 = 42u;
  unsigned c0, c1, s0, s1;
  tf2x32(key0, key1, 0u, 0u, c0, c1);
  tf2x32(key0, key1, 0u, 1u, s0, s1);
  key0 = c0; key1 = c1;
  unsigned k1a, k1b, k2a, k2b;
  tf2x32(s0, s1, 0u, 0u, k1a, k1b);
  tf2x32(s0, s1, 0u, 1u, k2a, k2b);
  unsigned h0, h1, l0, l1;
  tf2x32(k1a, k1b, 0u, 0u, h0, h1);
  tf2x32(k2a, k2b, 0u, 0u, l0, l1);
  unsigned hb = h0 ^ h1, lb = l0 ^ l1;
  unsigned span = 20000u;
  unsigned m1 = 65536u % span;
  unsigned mult = (unsigned)(((unsigned long long)m1 * m1) % span);  // 7296
  unsigned off32 = (hb % span) * mult + (lb % span);
  *i0p = (int)(off32 % span);
  sub[0] = 0u; sub[1] = 0u;
  for (int i = 1; i < KC; ++i) {
    tf2x32(key0, key1, 0u, 0u, c0, c1);
    tf2x32(key0, key1, 0u, 1u, s0, s1);
    key0 = c0; key1 = c1;
    sub[2*i] = s0; sub[2*i+1] = s1;
  }
}

// ---------------- K2: Q[step][i] = exp(gumbel) = -1/log(u) ----------------
__global__ __launch_bounds__(256) void k_gumbel(const unsigned* __restrict__ sub,
                                                float* __restrict__ Q) {
  int s = blockIdx.y + 1;
  int i = blockIdx.x * 256 + threadIdx.x;
  if (i >= NPT) return;
  unsigned o0, o1;
  tf2x32(sub[2*s], sub[2*s+1], 0u, (unsigned)i, o0, o1);
  unsigned bits = o0 ^ o1;
  unsigned fb = (bits >> 9) | 0x3f800000u;
  float u = __uint_as_float(fb) - 1.0f;
  if (u == 0.0f) u = 1.17549435e-38f;
  Q[(size_t)s*NPT + i] = -1.0f / logf(u);
}

// ---------------- K3: fused front — km (blk 0) | gemm+cl (blks 1..313) | sort (blk 314) ----
union FrontSM {
  struct { float red[16]; int redi[16]; int bsel; } km;
  struct { float As[64][64]; float Bs[64][HD]; } ge;       // 48KB (gemm phase)
  struct { float ht[64][HD]; float ps[64][HD]; } c2;       // 64KB (cl phase; aliases ge)
  struct { unsigned cnt[512][NT]; int tot[NT]; int base[NT]; } srt;
};

#define KPT 20
__global__ __launch_bounds__(1024) void k_front(const float* __restrict__ pos,
                                                const int* __restrict__ i0p,
                                                const float* __restrict__ Q,
                                                float* centsg,
                                                const float* __restrict__ emb,
                                                const float* __restrict__ W1,
                                                const float* __restrict__ b1,
                                                const float* __restrict__ protos,
                                                float* __restrict__ cl,
                                                const int* __restrict__ jt,
                                                int* order, int* tsv, int* offs) {
  __shared__ FrontSM sm;
  const int b = blockIdx.x, tid = threadIdx.x;
  const int lane = tid & 63, wv = tid >> 6;

  if (b == 0) {
    // ===== kmeans++ — Q software-pipelined (prefetch s+1 under step-s reduction) =====
    float dm[KPT], qv[KPT];
    const int i0 = *i0p;
    float cx = pos[2*i0], cy = pos[2*i0+1];
    if (tid == 0) { centsg[0] = cx; centsg[1] = cy; }
    #pragma unroll
    for (int u = 0; u < KPT; ++u) {
      int i = tid + (u << 10);
      dm[u] = 3.4e38f;
      qv[u] = (i < NPT) ? Q[(size_t)NPT + i] : 0.f;   // Q[1]
    }
    for (int s = 1; s < KC; ++s) {
      const float cc2 = cx*cx + cy*cy;
      float bsc = -3.4e38f; int bi = 0x7FFFFFFF;
      #pragma unroll
      for (int u = 0; u < KPT; ++u) {
        int i = tid + (u << 10);
        if (i < NPT) {
          float2 p = *(const float2*)(pos + 2*i);
          float d = fmaxf((p.x*p.x + p.y*p.y) + cc2 - 2.f*(p.x*cx + p.y*cy), 0.f);
          float nd = fminf(dm[u], d);
          dm[u] = nd;
          float sc = nd * qv[u];
          if (sc > bsc || (sc == bsc && i < bi)) { bsc = sc; bi = i; }
        }
      }
      // prefetch next step's Q row; latency hides under reduction+barriers
      if (s + 1 < KC) {
        const float* Qn = Q + (size_t)(s+1)*NPT;
        #pragma unroll
        for (int u = 0; u < KPT; ++u) {
          int i = tid + (u << 10);
          qv[u] = (i < NPT) ? Qn[i] : 0.f;
        }
      }
      for (int o = 32; o; o >>= 1) {
        float osc = __shfl_xor(bsc, o, 64);
        int   oid = __shfl_xor(bi, o, 64);
        if (osc > bsc || (osc == bsc && oid < bi)) { bsc = osc; bi = oid; }
      }
      if (lane == 0) { sm.km.red[wv] = bsc; sm.km.redi[wv] = bi; }
      __syncthreads();
      if (wv == 0) {
        float v2 = (lane < 16) ? sm.km.red[lane] : -3.4e38f;
        int  id2 = (lane < 16) ? sm.km.redi[lane] : 0x7FFFFFFF;
        #pragma unroll
        for (int o = 8; o; o >>= 1) {
          float ov = __shfl_xor(v2, o, 64);
          int   oi = __shfl_xor(id2, o, 64);
          if (ov > v2 || (ov == v2 && oi < id2)) { v2 = ov; id2 = oi; }
        }
        if (lane == 0) sm.km.bsel = id2;
      }
      __syncthreads();
      const int sel = sm.km.bsel;
      cx = pos[2*sel]; cy = pos[2*sel+1];
      if (tid == 0) { centsg[2*s] = cx; centsg[2*s+1] = cy; }
    }
  } else if (b <= GEB) {
    // ===== gemm tile (threads 0-255) + cl (all 1024), h stays in LDS =====
    const int m0 = (b - 1) * 64;
    const int tx = tid & 31, ty = (tid >> 5) & 7;
    float acc[8][4];
    #pragma unroll
    for (int a = 0; a < 8; ++a)
      #pragma unroll
      for (int c = 0; c < 4; ++c) acc[a][c] = 0.f;

    for (int kc = 0; kc < DIMK; kc += 64) {
      if (tid < 256) {
        #pragma unroll
        for (int it = 0; it < 4; ++it) {
          int f = it*256 + tid;
          int r = f >> 4;
          int kk = (f & 15) << 2;
          float4 v = make_float4(0.f,0.f,0.f,0.f);
          if (m0 + r < NPT)
            v = *(const float4*)(emb + (size_t)(m0 + r)*DIMK + kc + kk);
          sm.ge.As[kk+0][r] = v.x; sm.ge.As[kk+1][r] = v.y;
          sm.ge.As[kk+2][r] = v.z; sm.ge.As[kk+3][r] = v.w;
        }
        #pragma unroll
        for (int it = 0; it < 8; ++it) {
          int f = it*256 + tid;
          int kk = f >> 5;
          int cc = (f & 31) << 2;
          *(float4*)&sm.ge.Bs[kk][cc] = *(const float4*)(W1 + (size_t)(kc + kk)*HD + cc);
        }
      }
      __syncthreads();
      if (tid < 256) {
        #pragma unroll 8
        for (int kk = 0; kk < 64; ++kk) {
          float4 a0 = *(float4*)&sm.ge.As[kk][ty*8];
          float4 a1 = *(float4*)&sm.ge.As[kk][ty*8+4];
          float4 bb = *(float4*)&sm.ge.Bs[kk][tx*4];
          float av[8] = {a0.x,a0.y,a0.z,a0.w,a1.x,a1.y,a1.z,a1.w};
          float bv[4] = {bb.x,bb.y,bb.z,bb.w};
          #pragma unroll
          for (int a = 0; a < 8; ++a)
            #pragma unroll
            for (int c = 0; c < 4; ++c) acc[a][c] += av[a]*bv[c];
        }
      }
      __syncthreads();
    }
    // write h tile (selu) into LDS (aliases As/Bs; all reads completed)
    if (tid < 256) {
      const float SC = 1.0507009873554805f, AL = 1.6732632423543772f;
      #pragma unroll
      for (int a = 0; a < 8; ++a) {
        int r = ty*8 + a;
        #pragma unroll
        for (int c = 0; c < 4; ++c) {
          float x = acc[a][c] + b1[tx*4 + c];
          float v = (x > 0.f) ? x : AL * expm1f(x);
          sm.c2.ht[r][tx*4 + c] = SC * v;
        }
      }
    }
    // load protos (all threads)
    for (int f = tid; f < KC*HD; f += 1024)
      sm.c2.ps[f >> 7][f & 127] = protos[f];
    __syncthreads();
    // cl: 4096 (row,proto) pairs, 4 per thread; same per-pair FP order as k_cl
    #pragma unroll
    for (int q = 0; q < 4; ++q) {
      int p = tid + (q << 10);
      int r = p >> 6, j = p & 63;
      int gi = m0 + r;
      if (gi < NPT) {
        float dot = 0.f, hh = 0.f, pp = 0.f;
        #pragma unroll 8
        for (int d = 0; d < HD; ++d) {
          float a = sm.c2.ht[r][d], bb = sm.c2.ps[j][d];
          dot += a*bb; hh += a*a; pp += bb*bb;
        }
        float c = hh + pp - 2.f*dot;
        cl[(size_t)gi*KC + j] = fmaxf(c, 0.f);
      }
    }
  } else {
    // ===== counting sort (threads 0-511 active; all hit barriers) =====
    const int CHS = 40;
    const int r0 = tid*CHS, r1 = min(NPT, r0 + CHS);
    if (tid < 512) for (int t = 0; t < NT; ++t) sm.srt.cnt[tid][t] = 0;
    __syncthreads();
    if (tid < 512) for (int r = r0; r < r1; ++r) sm.srt.cnt[tid][jt[r]]++;
    __syncthreads();
    if (tid < NT) {
      unsigned s = 0;
      for (int i = 0; i < 512; ++i) s += sm.srt.cnt[i][tid];
      sm.srt.tot[tid] = (int)s;
    }
    __syncthreads();
    if (tid == 0) {
      int acc = 0;
      for (int t = 0; t < NT; ++t) { sm.srt.base[t] = acc; offs[t] = acc; acc += sm.srt.tot[t]; }
      offs[NT] = acc;
    }
    __syncthreads();
    if (tid < NT) {
      unsigned run = (unsigned)sm.srt.base[tid];
      for (int i = 0; i < 512; ++i) { unsigned c = sm.srt.cnt[i][tid]; sm.srt.cnt[i][tid] = run; run += c; }
    }
    __syncthreads();
    if (tid < 512) {
      for (int r = r0; r < r1; ++r) {
        int t = jt[r];
        unsigned p = sm.srt.cnt[tid][t]++;
        order[p] = r; tsv[p] = t;
      }
    }
  }
}

// ---------------- K6: one Lloyd iteration (grid LGB=64) ----------------
__global__ __launch_bounds__(512) void k_lloyd(const float* __restrict__ pos,
                                               float* centsg, float* llp, int first) {
  const int b = blockIdx.x, tid = threadIdx.x, lane = tid & 63, wv = tid >> 6;
  __shared__ float cents[KC][2];
  __shared__ float comb[192];
  __shared__ float wpart[8][192];
  __shared__ int asg[CPB];
  if (tid < KC) { cents[tid][0] = centsg[2*tid]; cents[tid][1] = centsg[2*tid+1]; }
  __syncthreads();
  if (!first) {
    if (tid < 192) {
      float s = 0.f;
      for (int bb = 0; bb < LGB; ++bb) s += llp[bb*192 + tid];
      comb[tid] = s;
    }
    __syncthreads();
    if (tid < KC) {
      float cn = comb[128 + tid];
      if (cn > 0.f) {
        float dv = fmaxf(cn, 1.f);
        cents[tid][0] = comb[tid] / dv;
        cents[tid][1] = comb[64 + tid] / dv;
      }
    }
    __syncthreads();
    if (b == 0 && tid < KC) {   // benign same-value race
      centsg[2*tid] = cents[tid][0]; centsg[2*tid+1] = cents[tid][1];
    }
  }
  const int base = b*CPB;
  const int pcnt = max(0, min(NPT - base, CPB));
  if (tid < pcnt) {
    int i = base + tid;
    float x = pos[2*i], y = pos[2*i+1];
    float bd = 3.4e38f; int bj = 0;
    #pragma unroll 4
    for (int j = 0; j < KC; ++j) {
      float cx = cents[j][0], cy = cents[j][1];
      float d = (x*x + y*y) + (cx*cx + cy*cy) - 2.f*(x*cx + y*cy);
      d = fmaxf(d, 0.f);
      if (d < bd) { bd = d; bj = j; }
    }
    asg[tid] = bj;
  }
  __syncthreads();
  {
    int r0 = 40*wv, r1 = min(pcnt, r0 + 40);
    float sx = 0.f, sy = 0.f, cn = 0.f;
    for (int r = r0; r < r1; ++r) {
      int a = asg[r]; int i = base + r;
      float x = pos[2*i], y = pos[2*i+1];
      if (lane == a) { sx += x; sy += y; cn += 1.f; }
    }
    wpart[wv][lane] = sx; wpart[wv][64+lane] = sy; wpart[wv][128+lane] = cn;
  }
  __syncthreads();
  if (tid < 192) {
    float s = 0.f;
    #pragma unroll
    for (int w8 = 0; w8 < 8; ++w8) s += wpart[w8][tid];
    llp[b*192 + tid] = s;
  }
}

// ---------------- K7: final cent combine + cost build + run table (grid NBLK) ----------------
__global__ __launch_bounds__(512) void k_cb(const float* __restrict__ pos,
                                            const float* __restrict__ cl,
                                            const int* __restrict__ order,
                                            const int* __restrict__ tsv,
                                            const float* __restrict__ centsg,
                                            const float* __restrict__ llp,
                                            float* __restrict__ Ls, int* runT) {
  const int b = blockIdx.x, tid = threadIdx.x, lane = tid & 63, wv = tid >> 6;
  __shared__ float cents[KC][2];
  __shared__ float comb[192];
  if (tid < KC) { cents[tid][0] = centsg[2*tid]; cents[tid][1] = centsg[2*tid+1]; }
  __syncthreads();
  if (tid < 192) {
    float s = 0.f;
    for (int bb = 0; bb < LGB; ++bb) s += llp[bb*192 + tid];
    comb[tid] = s;
  }
  __syncthreads();
  if (tid < KC) {
    float cn = comb[128 + tid];
    if (cn > 0.f) {
      float dv = fmaxf(cn, 1.f);
      cents[tid][0] = comb[tid] / dv;
      cents[tid][1] = comb[64 + tid] / dv;
    }
  }
  if (tid == 0) {
    int nrun = 0, prev = -1;
    int rt[3] = {-1,-1,-1};
    for (int u = 0; u < RPB; ++u) {
      int t = tsv[b*RPB + u];
      if (t != prev) { if (nrun < 3) rt[nrun] = t; nrun++; prev = t; }
    }
    runT[b*3+0] = rt[0]; runT[b*3+1] = rt[1]; runT[b*3+2] = rt[2];
  }
  __syncthreads();
  #pragma unroll
  for (int k = 0; k < 10; ++k) {
    int ii = b*RPB + wv*10 + k;
    int od = order[ii];
    float x = pos[2*od], y = pos[2*od+1];
    float cx = cents[lane][0], cy = cents[lane][1];
    float cs = fmaxf((x*x + y*y) + (cx*cx + cy*cy) - 2.f*(x*cx + y*cy), 0.f);
    float cle = cl[(size_t)od*KC + lane];
    Ls[(size_t)ii*KC + lane] = -(cs + 0.5f*cle) / 0.05f;
  }
}

// ---------------- K8: one Sinkhorn iteration (grid NBLK) ----------------
template<int FIRST>
__global__ __launch_bounds__(512) void k_sink(const float* __restrict__ Ls,
                                              float* __restrict__ logu,
                                              const int* __restrict__ offs,
                                              const int* __restrict__ runT,
                                              const int* __restrict__ tsv,
                                              float* __restrict__ PMb, float* __restrict__ PSb,
                                              float* __restrict__ PLm, float* __restrict__ PLs) {
  const int b = blockIdx.x, tid = threadIdx.x, lane = tid & 63, wv = tid >> 6;
  __shared__ float lvs[3][64];
  __shared__ float wpm[8][2][64], wps[8][2][64];
  __shared__ int   wri[8][2];
  __shared__ float plmw[8], plsw[8];
  __shared__ float lvl_sh;
  const int rt0 = runT[b*3+0], rt1 = runT[b*3+1], rt2 = runT[b*3+2];

  if (!FIRST) {
    if (wv < 3) {
      int t = (wv == 0) ? rt0 : ((wv == 1) ? rt1 : rt2);
      if (t >= 0) {
        float m = -3.4e38f, s = 0.f;
        int bb0 = offs[t] / RPB, bb1 = (offs[t+1] - 1) / RPB;
        for (int bb = bb0; bb <= bb1; ++bb) {
          #pragma unroll
          for (int q = 0; q < 3; ++q) {
            if (runT[bb*3+q] == t)
              lse_merge(m, s, PMb[(bb*3+q)*64 + lane], PSb[(bb*3+q)*64 + lane]);
          }
        }
        lvs[wv][lane] = -(__logf(s) + m);
      }
    } else if (wv == 3) {
      float m = -3.4e38f, s = 0.f;
      for (int bb = lane; bb < NBLK; bb += 64) lse_merge(m, s, PLm[bb], PLs[bb]);
      for (int o = 32; o; o >>= 1) {
        float m2 = __shfl_xor(m, o, 64), s2 = __shfl_xor(s, o, 64);
        lse_merge(m, s, m2, s2);
      }
      if (lane == 0) lvl_sh = logf((float)(NPT - NSLOT)) - (__logf(s) + m);
    }
    __syncthreads();
  }
  const float lvl = FIRST ? 0.f : lvl_sh;

  float am0 = -3.4e38f, as0 = 0.f, am1 = -3.4e38f, as1 = 0.f;
  int r0i = -1, r1i = -1;
  float lm = -3.4e38f, lss = 0.f;
  #pragma unroll
  for (int k = 0; k < 10; ++k) {
    int ii = b*RPB + wv*10 + k;
    int t = tsv[ii];
    int rq = (t == rt0) ? 0 : ((t == rt1) ? 1 : 2);
    float lvv = FIRST ? 0.f : lvs[rq][lane];
    float Lv = Ls[(size_t)ii*KC + lane];
    float x = Lv + lvv;
    float m = x;
    for (int o = 32; o; o >>= 1) m = fmaxf(m, __shfl_xor(m, o, 64));
    m = fmaxf(m, lvl);
    float e = __expf(x - m);
    for (int o = 32; o; o >>= 1) e += __shfl_xor(e, o, 64);
    e += __expf(lvl - m);
    float lu = -(__logf(e) + m);
    if (lane == 0) logu[ii] = lu;
    float cv = Lv + lu;
    if (r0i < 0 || rq == r0i) { r0i = rq; lse_merge(am0, as0, cv, 1.0f); }
    else                      { r1i = rq; lse_merge(am1, as1, cv, 1.0f); }
    lse_merge(lm, lss, lu, 1.0f);
  }
  wpm[wv][0][lane] = am0; wps[wv][0][lane] = as0;
  wpm[wv][1][lane] = am1; wps[wv][1][lane] = as1;
  if (lane == 0) { wri[wv][0] = r0i; wri[wv][1] = r1i; plmw[wv] = lm; plsw[wv] = lss; }
  __syncthreads();
  if (wv < 3) {
    float m = -3.4e38f, s = 0.f;
    for (int w8 = 0; w8 < 8; ++w8) {
      if (wri[w8][0] == wv) lse_merge(m, s, wpm[w8][0][lane], wps[w8][0][lane]);
      if (wri[w8][1] == wv) lse_merge(m, s, wpm[w8][1][lane], wps[w8][1][lane]);
    }
    PMb[(b*3+wv)*64 + lane] = m; PSb[(b*3+wv)*64 + lane] = s;
  } else if (wv == 3 && lane == 0) {
    float m = -3.4e38f, s = 0.f;
    #pragma unroll
    for (int w8 = 0; w8 < 8; ++w8) lse_merge(m, s, plmw[w8], plsw[w8]);
    PLm[b] = m; PLs[b] = s;
  }
}

// ---------------- K9: final log_v + vals ----------------
__global__ __launch_bounds__(512) void k_fin(const float* __restrict__ Ls,
                                             const float* __restrict__ logu,
                                             const int* __restrict__ offs,
                                             const int* __restrict__ runT,
                                             const int* __restrict__ tsv,
                                             const int* __restrict__ order,
                                             const float* __restrict__ PMb,
                                             const float* __restrict__ PSb,
                                             float* __restrict__ vals) {
  const int b = blockIdx.x, tid = threadIdx.x, lane = tid & 63, wv = tid >> 6;
  __shared__ float lvs[3][64];
  const int rt0 = runT[b*3+0], rt1 = runT[b*3+1], rt2 = runT[b*3+2];
  if (wv < 3) {
    int t = (wv == 0) ? rt0 : ((wv == 1) ? rt1 : rt2);
    if (t >= 0) {
      float m = -3.4e38f, s = 0.f;
      int bb0 = offs[t] / RPB, bb1 = (offs[t+1] - 1) / RPB;
      for (int bb = bb0; bb <= bb1; ++bb) {
        #pragma unroll
        for (int q = 0; q < 3; ++q) {
          if (runT[bb*3+q] == t)
            lse_merge(m, s, PMb[(bb*3+q)*64 + lane], PSb[(bb*3+q)*64 + lane]);
        }
      }
      lvs[wv][lane] = -(__logf(s) + m);
    }
  }
  __syncthreads();
  #pragma unroll
  for (int k = 0; k < 10; ++k) {
    int ii = b*RPB + wv*10 + k;
    int t = tsv[ii];
    int rq = (t == rt0) ? 0 : ((t == rt1) ? 1 : 2);
    vals[(size_t)order[ii]*KC + lane] =
        __expf(Ls[(size_t)ii*KC + lane] + lvs[rq][lane] + logu[ii]);
  }
}

// ---------------- K10: expand vals into full T + logits = log(vals+1e-8) ----------------
__global__ __launch_bounds__(256) void k_T(float* __restrict__ vals,
                                           const int* __restrict__ jt,
                                           float* __restrict__ T) {
  __shared__ float v[KC];
  const int i = blockIdx.x;
  const int tid = threadIdx.x;
  if (tid < KC) v[tid] = vals[(size_t)i*KC + tid];
  __syncthreads();
  const int t = jt[i];
  for (int e = tid; e < NSLOT; e += 256) {
    int j = e / NT;
    int tt = e - j*NT;
    T[(size_t)i*NSLOT + e] = (tt == t) ? v[j] : 0.0f;
  }
  if (tid < KC) vals[(size_t)i*KC + tid] = logf(v[tid] + 1e-8f);
}

extern "C" void kernel_launch(void* const* d_in, const int* in_sizes, int n_in,
                              void* d_out, int out_size, void* d_ws, size_t ws_size,
                              hipStream_t stream) {
  const float* emb    = (const float*)d_in[0];
  const float* pos    = (const float*)d_in[1];
  const float* W1     = (const float*)d_in[2];
  const float* b1     = (const float*)d_in[3];
  const float* protos = (const float*)d_in[4];
  const int*   jt     = (const int*)d_in[5];

  float* out  = (float*)d_out;
  float* vals = out;
  float* T    = out + (size_t)NPT*KC;
  float* TS   = T;

  unsigned* sub = (unsigned*)(TS + OFF_SUB);
  int* i0p    = (int*)(TS + OFF_I0);
  int* order  = (int*)(TS + OFF_ORDER);
  int* tsv    = (int*)(TS + OFF_TSV);
  int* offs   = (int*)(TS + OFF_OFFS);
  int* runT   = (int*)(TS + OFF_RUNT);
  float* centsg = TS + OFF_CENTS;
  float* llp  = TS + OFF_LLP;
  float* Ls   = TS + OFF_LS;
  float* logu = TS + OFF_LOGU;
  float* PMb  = TS + OFF_PMB;
  float* PSb  = TS + OFF_PSB;
  float* PLm  = TS + OFF_PLM;
  float* PLs  = TS + OFF_PLS;

  hipLaunchKernelGGL(k_keys, dim3(1), dim3(64), 0, stream, sub, i0p);
  hipLaunchKernelGGL(k_gumbel, dim3((NPT + 255)/256, KC - 1), dim3(256), 0, stream,
                     sub, TS + OFF_Q);
  hipLaunchKernelGGL(k_front, dim3(FBLK), dim3(1024), 0, stream,
                     pos, i0p, TS + OFF_Q, centsg,
                     emb, W1, b1, protos, TS + OFF_CL,
                     jt, order, tsv, offs);

  for (int it = 0; it < 10; ++it)
    hipLaunchKernelGGL(k_lloyd, dim3(LGB), dim3(512), 0, stream,
                       pos, centsg, llp, (it == 0) ? 1 : 0);

  hipLaunchKernelGGL(k_cb, dim3(NBLK), dim3(512), 0, stream,
                     pos, TS + OFF_CL, order, tsv, centsg, llp, Ls, runT);

  hipLaunchKernelGGL(k_sink<1>, dim3(NBLK), dim3(512), 0, stream,
                     Ls, logu, offs, runT, tsv, PMb, PSb, PLm, PLs);
  for (int it = 1; it < SINK_IT; ++it)
    hipLaunchKernelGGL(k_sink<0>, dim3(NBLK), dim3(512), 0, stream,
                       Ls, logu, offs, runT, tsv, PMb, PSb, PLm, PLs);

  hipLaunchKernelGGL(k_fin, dim3(NBLK), dim3(512), 0, stream,
                     Ls, logu, offs, runT, tsv, order, PMb, PSb, vals);

  hipLaunchKernelGGL(k_T, dim3(NPT), dim3(256), 0, stream, vals, jt, T);
}